// Round 8
// baseline (727.630 us; speedup 1.0000x reference)
//
#include <hip/hip_runtime.h>
#include <hip/hip_bf16.h>
#include <math.h>

// Problem dims
#define NB 256
#define NT 512
#define NF 128
#define NCOH 64         // coh_pts
#define NIN 192         // F + coh_pts
#define NBS 384         // 3*bulk_pts
#define NROWS (NB*NT)   // 131072

// Material constants (match fp64->fp32 of reference)
#define C11 1098.9010989010989f
#define C12 329.67032967032966f
#define C33 384.61538461538464f
#define H3G 1253.8461538461538f   // 3*G + HARD

typedef __attribute__((ext_vector_type(8))) short bf16x8;   // 8 bf16 = 4 VGPR
typedef __attribute__((ext_vector_type(4))) float f32x4;    // MFMA acc
typedef __attribute__((ext_vector_type(4))) short short4v;

// s_waitcnt with only vmcnt constrained (expcnt=7, lgkmcnt=15 = no-wait)
#define WAITCNT_VM(N) __builtin_amdgcn_s_waitcnt(0x0F70 | ((N) & 15) | (((N) >> 4) << 14))

// bf16 hi/lo split operands (rewritten in full every call -> no stale state)
__device__ unsigned short g_Ahi[(size_t)NROWS * NIN];   // concat(x, dmg) hi
__device__ unsigned short g_Alo[(size_t)NROWS * NIN];   // concat(x, dmg) lo
__device__ unsigned short g_Bhi[NBS * NIN];             // D-folded W12 hi
__device__ unsigned short g_Blo[NBS * NIN];             // D-folded W12 lo

static __device__ __forceinline__ unsigned short f2bf(float v) {
    __hip_bfloat16 h = __float2bfloat16(v);
    return *reinterpret_cast<unsigned short*>(&h);
}
static __device__ __forceinline__ float bf2f(unsigned short u) {
    __hip_bfloat16 h; *reinterpret_cast<unsigned short*>(&h) = u;
    return __bfloat162float(h);
}
static __device__ __forceinline__ void async_copy16(const void* g, void* l) {
    __builtin_amdgcn_global_load_lds(
        (const __attribute__((address_space(1))) unsigned int*)g,
        (__attribute__((address_space(3))) unsigned int*)l, 16, 0, 0);
}

// ---------------------------------------------------------------------------
// K0: fold plane-stress D into W12 and split to bf16 hi/lo.
// ---------------------------------------------------------------------------
__global__ __launch_bounds__(256) void k0_w12(const float* __restrict__ W12)
{
    const int idx = blockIdx.x * 256 + threadIdx.x;   // < 384*192 = 73728
    const int r = idx / NIN, i = idx - r * NIN;
    const int p = r / 3, j = r - 3 * p;
    const float* w = W12 + (size_t)(3 * p) * NIN;
    float v;
    if (j == 0)      v = C11 * w[i]           + C12 * w[NIN + i];
    else if (j == 1) v = C12 * w[i]           + C11 * w[NIN + i];
    else             v = C33 * w[2 * NIN + i];
    unsigned short h = f2bf(v);
    g_Bhi[idx] = h;
    g_Blo[idx] = f2bf(v - bf2f(h));
}

// ---------------------------------------------------------------------------
// KX: split x (fp32) into bf16 hi/lo -> cols 0..127 of the A operand buffers.
// ---------------------------------------------------------------------------
__global__ __launch_bounds__(256) void kx_split(const float* __restrict__ x)
{
    const int idx = blockIdx.x * 256 + threadIdx.x;   // NROWS*32
    const int row = idx >> 5, c4 = (idx & 31) * 4;
    float4 v = *(const float4*)(x + (size_t)row * NF + c4);
    float vv[4] = {v.x, v.y, v.z, v.w};
    short4v hv, lv;
#pragma unroll
    for (int i = 0; i < 4; ++i) {
        unsigned short h = f2bf(vv[i]);
        hv[i] = (short)h;
        lv[i] = (short)f2bf(vv[i] - bf2f(h));
    }
    const size_t o = (size_t)row * NIN + c4;
    *(short4v*)(g_Ahi + o) = hv;
    *(short4v*)(g_Alo + o) = lv;
}

// ---------------------------------------------------------------------------
// K1: jumps = leaky_relu(x @ W11^T + b11); d_new from pairs. fp32, unchanged.
// ---------------------------------------------------------------------------
__global__ __launch_bounds__(256, 2) void k1_fc11(
    const float* __restrict__ x, const float* __restrict__ W11,
    const float* __restrict__ b11, float* __restrict__ dnew)
{
    __shared__ float As[16][132];
    __shared__ float Bs[16][128];
    const int tid = threadIdx.x;
    const int row0 = blockIdx.x * 128;
    const int tx = tid & 15, ty = tid >> 4;

    float acc[8][8];
#pragma unroll
    for (int i = 0; i < 8; ++i)
#pragma unroll
        for (int j = 0; j < 8; ++j) acc[i][j] = 0.0f;

    const int lr = tid >> 2;
    const int lk = (tid & 3) * 4;
    const int bn = tid >> 1;
    const int bk = (tid & 1) * 8;

    for (int kc = 0; kc < 8; ++kc) {
        const int k0 = kc * 16;
        float4 a0 = *(const float4*)(x + (size_t)(row0 + lr) * NF + k0 + lk);
        float4 a1 = *(const float4*)(x + (size_t)(row0 + lr + 64) * NF + k0 + lk);
        float4 w0 = *(const float4*)(W11 + (size_t)bn * NF + k0 + bk);
        float4 w1 = *(const float4*)(W11 + (size_t)bn * NF + k0 + bk + 4);
        __syncthreads();
        As[lk+0][lr] = a0.x; As[lk+1][lr] = a0.y; As[lk+2][lr] = a0.z; As[lk+3][lr] = a0.w;
        As[lk+0][lr+64] = a1.x; As[lk+1][lr+64] = a1.y; As[lk+2][lr+64] = a1.z; As[lk+3][lr+64] = a1.w;
        Bs[bk+0][bn] = w0.x; Bs[bk+1][bn] = w0.y; Bs[bk+2][bn] = w0.z; Bs[bk+3][bn] = w0.w;
        Bs[bk+4][bn] = w1.x; Bs[bk+5][bn] = w1.y; Bs[bk+6][bn] = w1.z; Bs[bk+7][bn] = w1.w;
        __syncthreads();
#pragma unroll
        for (int k = 0; k < 16; ++k) {
            float4 av0 = *(const float4*)&As[k][8*ty];
            float4 av1 = *(const float4*)&As[k][8*ty+4];
            float4 bv0 = *(const float4*)&Bs[k][8*tx];
            float4 bv1 = *(const float4*)&Bs[k][8*tx+4];
            float a[8] = {av0.x,av0.y,av0.z,av0.w,av1.x,av1.y,av1.z,av1.w};
            float b[8] = {bv0.x,bv0.y,bv0.z,bv0.w,bv1.x,bv1.y,bv1.z,bv1.w};
#pragma unroll
            for (int i = 0; i < 8; ++i)
#pragma unroll
                for (int j = 0; j < 8; ++j)
                    acc[i][j] = fmaf(a[i], b[j], acc[i][j]);
        }
    }

#pragma unroll
    for (int i = 0; i < 8; ++i) {
        const int row = row0 + 8*ty + i;
        float dnv[4];
#pragma unroll
        for (int jp = 0; jp < 4; ++jp) {
            float z0 = acc[i][2*jp]   + b11[8*tx + 2*jp];
            float z1 = acc[i][2*jp+1] + b11[8*tx + 2*jp+1];
            float jn = fmaxf(z0, 0.0f);
            float js = (z1 > 0.0f) ? z1 : 0.01f * z1;
            float delta = sqrtf(jn*jn + js*js + 1e-12f);
            float dn = 0.1f * (delta - 0.01f) / (fmaxf(delta, 1e-12f) * 0.09f);
            dnv[jp] = fminf(fmaxf(dn, 0.0f), 1.0f);
        }
        float4 dv; dv.x = dnv[0]; dv.y = dnv[1]; dv.z = dnv[2]; dv.w = dnv[3];
        *(float4*)(dnew + (size_t)row * NCOH + 4*tx) = dv;
    }
}

// ---------------------------------------------------------------------------
// K2: cummax over t; emit dmg as bf16 hi/lo into cols 128..191 of A buffers.
// ---------------------------------------------------------------------------
__global__ __launch_bounds__(64) void k2_cummax(const float* __restrict__ d)
{
    const int b = blockIdx.x;          // one batch per block
    const int c = threadIdx.x;         // 0..63
    const float* p = d + (size_t)b * NT * NCOH + c;
    unsigned short* ah = g_Ahi + (size_t)b * NT * NIN + NF + c;
    unsigned short* al = g_Alo + (size_t)b * NT * NIN + NF + c;

    float buf[8];
#pragma unroll
    for (int u = 0; u < 8; ++u) buf[u] = p[(size_t)u * NCOH];

    float m = 0.0f;
#pragma unroll 8
    for (int t = 0; t < NT - 8; ++t) {
        const int sl = t & 7;
        float v = buf[sl];
        buf[sl] = p[(size_t)(t + 8) * NCOH];
        m = fmaxf(m, v);
        unsigned short h = f2bf(m);
        ah[(size_t)t * NIN] = h;
        al[(size_t)t * NIN] = f2bf(m - bf2f(h));
    }
#pragma unroll
    for (int t = NT - 8; t < NT; ++t) {
        m = fmaxf(m, buf[t & 7]);
        unsigned short h = f2bf(m);
        ah[(size_t)t * NIN] = h;
        al[(size_t)t * NIN] = f2bf(m - bf2f(h));
    }
}

// ---------------------------------------------------------------------------
// K3: sig_tr = A @ B^T via bf16x3 MFMA (Ahi*Bhi + Ahi*Blo + Alo*Bhi = K=576).
// R6 structure (best of 3 tried: 153 vs 154 barrier / 190 all-register):
// triple-buffered LDS chunks, prefetch 1 ahead with global_load_lds,
// raw s_waitcnt vmcnt(4) + raw s_barrier, ONE barrier per chunk.
// ---------------------------------------------------------------------------
__global__ __launch_bounds__(256) void k3_mfma(float* __restrict__ sig)
{
    __shared__ unsigned short As[3][128 * 32];   // 3 x 8 KB
    __shared__ unsigned short Bs[3][128 * 32];   // 3 x 8 KB

    const int tid = threadIdx.x;
    const int lane = tid & 63, w = tid >> 6;
    const int m0 = blockIdx.y * 128;
    const int n0 = blockIdx.x * 128;          // x fastest: 3 n-tiles share A rows
    const int wm = (w >> 1) * 64, wn = (w & 1) * 64;
    const int fr = lane & 15, fq = lane >> 4;

    f32x4 acc[4][4];
#pragma unroll
    for (int mi = 0; mi < 4; ++mi)
#pragma unroll
        for (int ni = 0; ni < 4; ++ni) acc[mi][ni] = (f32x4){0.f, 0.f, 0.f, 0.f};

    // staging: 8 KB per operand chunk / 256 threads = 2 x 16 B per thread
    const int off0 = tid * 16;            // bytes in [0, 4096)
    const int off1 = tid * 16 + 4096;     // bytes in [4096, 8192)
    const int r0 = off0 >> 6, q0 = (off0 >> 4) & 3;
    const int r1 = off1 >> 6, q1 = (off1 >> 4) & 3;

    const unsigned short* Aseg[3] = {g_Ahi, g_Ahi, g_Alo};
    const unsigned short* Bseg[3] = {g_Bhi, g_Blo, g_Bhi};

    // chunk schedule: c = 0..17 -> seg = c/6, kb = (c%6)*32 (tracked incrementally)
    int seg_n = 0, kb_n = 0;   // of the NEXT chunk to issue

    // issue chunk 0 into buf 0
    {
        const unsigned short* Ag = Aseg[0];
        const unsigned short* Bg = Bseg[0];
        async_copy16(Ag + (size_t)(m0 + r0) * NIN + q0 * 8, (char*)As[0] + off0);
        async_copy16(Ag + (size_t)(m0 + r1) * NIN + q1 * 8, (char*)As[0] + off1);
        async_copy16(Bg + (size_t)(n0 + r0) * NIN + q0 * 8, (char*)Bs[0] + off0);
        async_copy16(Bg + (size_t)(n0 + r1) * NIN + q1 * 8, (char*)Bs[0] + off1);
        kb_n = 32;
    }

    int buf = 0;
#pragma unroll 1
    for (int c = 0; c < 17; ++c) {
        // prefetch chunk c+1 into buf (c+1)%3
        const int nbuf = (buf == 2) ? 0 : buf + 1;
        {
            const unsigned short* Ag = Aseg[seg_n];
            const unsigned short* Bg = Bseg[seg_n];
            async_copy16(Ag + (size_t)(m0 + r0) * NIN + kb_n + q0 * 8, (char*)As[nbuf] + off0);
            async_copy16(Ag + (size_t)(m0 + r1) * NIN + kb_n + q1 * 8, (char*)As[nbuf] + off1);
            async_copy16(Bg + (size_t)(n0 + r0) * NIN + kb_n + q0 * 8, (char*)Bs[nbuf] + off0);
            async_copy16(Bg + (size_t)(n0 + r1) * NIN + kb_n + q1 * 8, (char*)Bs[nbuf] + off1);
            kb_n += 32;
            if (kb_n == NIN) { kb_n = 0; ++seg_n; }
        }
        WAITCNT_VM(4);                       // own chunk-c copies landed
        __builtin_amdgcn_s_barrier();        // everyone's chunk-c landed

        bf16x8 a[4], b[4];
#pragma unroll
        for (int mi = 0; mi < 4; ++mi)
            a[mi] = *(bf16x8*)&As[buf][(wm + mi * 16 + fr) * 32 + fq * 8];
#pragma unroll
        for (int ni = 0; ni < 4; ++ni)
            b[ni] = *(bf16x8*)&Bs[buf][(wn + ni * 16 + fr) * 32 + fq * 8];
#pragma unroll
        for (int mi = 0; mi < 4; ++mi)
#pragma unroll
            for (int ni = 0; ni < 4; ++ni)
                acc[mi][ni] = __builtin_amdgcn_mfma_f32_16x16x32_bf16(
                    a[mi], b[ni], acc[mi][ni], 0, 0, 0);
        buf = nbuf;
    }

    // last chunk (c = 17), buf = 17%3 = 2
    WAITCNT_VM(0);
    __builtin_amdgcn_s_barrier();
    {
        bf16x8 a[4], b[4];
#pragma unroll
        for (int mi = 0; mi < 4; ++mi)
            a[mi] = *(bf16x8*)&As[buf][(wm + mi * 16 + fr) * 32 + fq * 8];
#pragma unroll
        for (int ni = 0; ni < 4; ++ni)
            b[ni] = *(bf16x8*)&Bs[buf][(wn + ni * 16 + fr) * 32 + fq * 8];
#pragma unroll
        for (int mi = 0; mi < 4; ++mi)
#pragma unroll
            for (int ni = 0; ni < 4; ++ni)
                acc[mi][ni] = __builtin_amdgcn_mfma_f32_16x16x32_bf16(
                    a[mi], b[ni], acc[mi][ni], 0, 0, 0);
    }

    // epilogue: C/D layout col=lane&15, row=(lane>>4)*4+reg  [m89-verified]
    const int er = fq * 4, ec = fr;
#pragma unroll
    for (int mi = 0; mi < 4; ++mi)
#pragma unroll
        for (int ni = 0; ni < 4; ++ni)
#pragma unroll
            for (int r = 0; r < 4; ++r)
                sig[(size_t)(m0 + wm + mi * 16 + er + r) * NBS + (n0 + wn + ni * 16 + ec)]
                    = acc[mi][ni][r];
}

// ---------------------------------------------------------------------------
// K45: fused plasticity scan + fc2 + softplus. One block per batch b,
// 128 threads. Chunked over t (64 steps): phase A = private ep-scan writing
// scaled triples to LDS (ep in registers across chunks, depth-16 global
// prefetch of read-only sig_tr); barrier; phase B = 2 threads/row x 3 outputs
// each from LDS rows + W2s; barrier. 16 barriers total (R2 lesson: per-t
// sync was fatal; per-64-t is amortized). Deletes k4's 196 MB write and
// k5's 196 MB re-read.
// ---------------------------------------------------------------------------
#define TC 64
__global__ __launch_bounds__(128) void k45_fused(
    const float* __restrict__ sig, const float* __restrict__ W2,
    float* __restrict__ out)
{
    __shared__ float W2s[6][NBS];        // 9216 B
    __shared__ float rows[TC][388];      // 99328 B (stride 388: 16B-aligned rows)

    const int tid = threadIdx.x;         // 0..127 == chain p
    const int b = blockIdx.x;
    for (int i = tid; i < 6 * NBS; i += 128) W2s[i / NBS][i % NBS] = W2[i];

    const float* s = sig + (size_t)b * NT * NBS + 3 * tid;
    float* outb = out + (size_t)b * NT * 6;

    // depth-16 circular register prefetch (sig_tr is read-only here)
    float px[16], py[16], pz[16];
#pragma unroll
    for (int u = 0; u < 16; ++u) {
        const float* sp = s + (size_t)u * NBS;
        px[u] = sp[0]; py[u] = sp[1]; pz[u] = sp[2];
    }

    const int t2 = tid >> 1;             // phase-B row (0..63)
    const int oh = (tid & 1) * 3;        // phase-B output half (0 or 3)

    float ep = 0.0f;
    __syncthreads();                     // W2s ready

#pragma unroll 1
    for (int chunk = 0; chunk < NT / TC; ++chunk) {
        // ---- phase A: scan 64 timesteps into LDS ----
#pragma unroll 8
        for (int i = 0; i < TC; ++i) {
            const int t = chunk * TC + i;
            const int sl = t & 15;
            float sxx = px[sl], syy = py[sl], txy = pz[sl];
            if (t + 16 < NT) {
                const float* sp = s + (size_t)(t + 16) * NBS;
                px[sl] = sp[0]; py[sl] = sp[1]; pz[sl] = sp[2];
            }
            float seq = sqrtf(sxx*sxx - sxx*syy + syy*syy + 3.0f*txy*txy + 1e-12f);
            float fy = seq - (10.0f + 100.0f * ep);
            float dep = (fy > 0.0f) ? (fy / H3G) : 0.0f;
            ep += dep;
            float scale = (fy > 0.0f) ? ((10.0f + 100.0f * ep) / seq) : 1.0f;
            rows[i][3 * tid + 0] = sxx * scale;
            rows[i][3 * tid + 1] = syy * scale;
            rows[i][3 * tid + 2] = txy * scale;
        }
        __syncthreads();

        // ---- phase B: out rows from LDS (2 threads/row, 3 outs each) ----
        float a0 = 0.f, a1 = 0.f, a2 = 0.f;
#pragma unroll 8
        for (int q = 0; q < NBS / 4; ++q) {
            float4 v = *(const float4*)&rows[t2][4 * q];
            float4 w0 = *(const float4*)&W2s[oh + 0][4 * q];
            float4 w1 = *(const float4*)&W2s[oh + 1][4 * q];
            float4 w2 = *(const float4*)&W2s[oh + 2][4 * q];
            a0 = fmaf(v.x, w0.x, a0); a0 = fmaf(v.y, w0.y, a0);
            a0 = fmaf(v.z, w0.z, a0); a0 = fmaf(v.w, w0.w, a0);
            a1 = fmaf(v.x, w1.x, a1); a1 = fmaf(v.y, w1.y, a1);
            a1 = fmaf(v.z, w1.z, a1); a1 = fmaf(v.w, w1.w, a1);
            a2 = fmaf(v.x, w2.x, a2); a2 = fmaf(v.y, w2.y, a2);
            a2 = fmaf(v.z, w2.z, a2); a2 = fmaf(v.w, w2.w, a2);
        }
        const int t = chunk * TC + t2;
        float* op = outb + (size_t)t * 6 + oh;
        op[0] = fmaxf(a0, 0.0f) + log1pf(expf(-fabsf(a0)));
        op[1] = fmaxf(a1, 0.0f) + log1pf(expf(-fabsf(a1)));
        op[2] = fmaxf(a2, 0.0f) + log1pf(expf(-fabsf(a2)));
        __syncthreads();                 // protect rows[] before next phase A
    }
}

// ---------------------------------------------------------------------------
extern "C" void kernel_launch(void* const* d_in, const int* in_sizes, int n_in,
                              void* d_out, int out_size, void* d_ws, size_t ws_size,
                              hipStream_t stream)
{
    const float* x   = (const float*)d_in[0];
    const float* W11 = (const float*)d_in[1];
    const float* b11 = (const float*)d_in[2];
    const float* W12 = (const float*)d_in[3];
    const float* W2  = (const float*)d_in[4];
    float* out = (float*)d_out;

    // ws layout: dnew [NROWS*64] fp32 (32MB) | sig [NROWS*384] fp32 (192MB)
    float* dnew = (float*)d_ws;
    float* sig  = (float*)((char*)d_ws + (size_t)NROWS * NCOH * sizeof(float));

    k0_w12<<<(NBS * NIN) / 256, 256, 0, stream>>>(W12);
    kx_split<<<(NROWS * 32) / 256, 256, 0, stream>>>(x);
    k1_fc11<<<NROWS / 128, 256, 0, stream>>>(x, W11, b11, dnew);
    k2_cummax<<<NB, 64, 0, stream>>>(dnew);
    k3_mfma<<<dim3(3, NROWS / 128), 256, 0, stream>>>(sig);
    k45_fused<<<NB, 128, 0, stream>>>(sig, W2, out);
}

// Round 9
// 485.001 us; speedup vs baseline: 1.5003x; 1.5003x over previous
//
#include <hip/hip_runtime.h>
#include <hip/hip_bf16.h>
#include <math.h>

// Problem dims
#define NB 256
#define NT 512
#define NF 128
#define NCOH 64         // coh_pts
#define NIN 192         // F + coh_pts
#define NBS 384         // 3*bulk_pts
#define NROWS (NB*NT)   // 131072

// Material constants (match fp64->fp32 of reference)
#define C11 1098.9010989010989f
#define C12 329.67032967032966f
#define C33 384.61538461538464f
#define H3G 1253.8461538461538f   // 3*G + HARD

typedef __attribute__((ext_vector_type(8))) short bf16x8;   // 8 bf16 = 4 VGPR
typedef __attribute__((ext_vector_type(4))) float f32x4;    // MFMA acc
typedef __attribute__((ext_vector_type(4))) short short4v;
typedef __attribute__((ext_vector_type(8))) unsigned short ushort8v;

// s_waitcnt with only vmcnt constrained (expcnt=7, lgkmcnt=15 = no-wait)
#define WAITCNT_VM(N) __builtin_amdgcn_s_waitcnt(0x0F70 | ((N) & 15) | (((N) >> 4) << 14))

// bf16 hi/lo split operands (rewritten in full every call -> no stale state)
__device__ unsigned short g_Ahi[(size_t)NROWS * NIN];   // concat(x, dmg) hi
__device__ unsigned short g_Alo[(size_t)NROWS * NIN];   // concat(x, dmg) lo
__device__ unsigned short g_Bhi[NBS * NIN];             // D-folded W12 hi
__device__ unsigned short g_Blo[NBS * NIN];             // D-folded W12 lo

static __device__ __forceinline__ unsigned short f2bf(float v) {
    __hip_bfloat16 h = __float2bfloat16(v);
    return *reinterpret_cast<unsigned short*>(&h);
}
static __device__ __forceinline__ float bf2f(unsigned short u) {
    unsigned int x = ((unsigned int)u) << 16;
    return *reinterpret_cast<float*>(&x);
}
static __device__ __forceinline__ void async_copy16(const void* g, void* l) {
    __builtin_amdgcn_global_load_lds(
        (const __attribute__((address_space(1))) unsigned int*)g,
        (__attribute__((address_space(3))) unsigned int*)l, 16, 0, 0);
}

// ---------------------------------------------------------------------------
// K0: fold plane-stress D into W12 and split to bf16 hi/lo.
// ---------------------------------------------------------------------------
__global__ __launch_bounds__(256) void k0_w12(const float* __restrict__ W12)
{
    const int idx = blockIdx.x * 256 + threadIdx.x;   // < 384*192 = 73728
    const int r = idx / NIN, i = idx - r * NIN;
    const int p = r / 3, j = r - 3 * p;
    const float* w = W12 + (size_t)(3 * p) * NIN;
    float v;
    if (j == 0)      v = C11 * w[i]           + C12 * w[NIN + i];
    else if (j == 1) v = C12 * w[i]           + C11 * w[NIN + i];
    else             v = C33 * w[2 * NIN + i];
    unsigned short h = f2bf(v);
    g_Bhi[idx] = h;
    g_Blo[idx] = f2bf(v - bf2f(h));
}

// ---------------------------------------------------------------------------
// K1: jumps = leaky_relu(x @ W11^T + b11); d_new from pairs. fp32 GEMM.
// R9: also emits the bf16 hi/lo split of x into A-buffer cols 0..127 during
// staging (x flows through registers anyway) — kx_split kernel deleted.
// Each (row, col) is loaded by exactly one thread across the kc loop.
// ---------------------------------------------------------------------------
__global__ __launch_bounds__(256, 2) void k1_fc11(
    const float* __restrict__ x, const float* __restrict__ W11,
    const float* __restrict__ b11, float* __restrict__ dnew)
{
    __shared__ float As[16][132];
    __shared__ float Bs[16][128];
    const int tid = threadIdx.x;
    const int row0 = blockIdx.x * 128;
    const int tx = tid & 15, ty = tid >> 4;

    float acc[8][8];
#pragma unroll
    for (int i = 0; i < 8; ++i)
#pragma unroll
        for (int j = 0; j < 8; ++j) acc[i][j] = 0.0f;

    const int lr = tid >> 2;
    const int lk = (tid & 3) * 4;
    const int bn = tid >> 1;
    const int bk = (tid & 1) * 8;

    for (int kc = 0; kc < 8; ++kc) {
        const int k0 = kc * 16;
        float4 a0 = *(const float4*)(x + (size_t)(row0 + lr) * NF + k0 + lk);
        float4 a1 = *(const float4*)(x + (size_t)(row0 + lr + 64) * NF + k0 + lk);
        float4 w0 = *(const float4*)(W11 + (size_t)bn * NF + k0 + bk);
        float4 w1 = *(const float4*)(W11 + (size_t)bn * NF + k0 + bk + 4);

        // bf16 hi/lo split of the freshly loaded x values -> A operand buffers
        {
            float v0[4] = {a0.x, a0.y, a0.z, a0.w};
            float v1[4] = {a1.x, a1.y, a1.z, a1.w};
            short4v h0, l0, h1, l1;
#pragma unroll
            for (int i = 0; i < 4; ++i) {
                unsigned short h = f2bf(v0[i]);
                h0[i] = (short)h; l0[i] = (short)f2bf(v0[i] - bf2f(h));
                h = f2bf(v1[i]);
                h1[i] = (short)h; l1[i] = (short)f2bf(v1[i] - bf2f(h));
            }
            const size_t o0 = (size_t)(row0 + lr) * NIN + k0 + lk;
            const size_t o1 = (size_t)(row0 + lr + 64) * NIN + k0 + lk;
            *(short4v*)(g_Ahi + o0) = h0;
            *(short4v*)(g_Alo + o0) = l0;
            *(short4v*)(g_Ahi + o1) = h1;
            *(short4v*)(g_Alo + o1) = l1;
        }

        __syncthreads();
        As[lk+0][lr] = a0.x; As[lk+1][lr] = a0.y; As[lk+2][lr] = a0.z; As[lk+3][lr] = a0.w;
        As[lk+0][lr+64] = a1.x; As[lk+1][lr+64] = a1.y; As[lk+2][lr+64] = a1.z; As[lk+3][lr+64] = a1.w;
        Bs[bk+0][bn] = w0.x; Bs[bk+1][bn] = w0.y; Bs[bk+2][bn] = w0.z; Bs[bk+3][bn] = w0.w;
        Bs[bk+4][bn] = w1.x; Bs[bk+5][bn] = w1.y; Bs[bk+6][bn] = w1.z; Bs[bk+7][bn] = w1.w;
        __syncthreads();
#pragma unroll
        for (int k = 0; k < 16; ++k) {
            float4 av0 = *(const float4*)&As[k][8*ty];
            float4 av1 = *(const float4*)&As[k][8*ty+4];
            float4 bv0 = *(const float4*)&Bs[k][8*tx];
            float4 bv1 = *(const float4*)&Bs[k][8*tx+4];
            float a[8] = {av0.x,av0.y,av0.z,av0.w,av1.x,av1.y,av1.z,av1.w};
            float b[8] = {bv0.x,bv0.y,bv0.z,bv0.w,bv1.x,bv1.y,bv1.z,bv1.w};
#pragma unroll
            for (int i = 0; i < 8; ++i)
#pragma unroll
                for (int j = 0; j < 8; ++j)
                    acc[i][j] = fmaf(a[i], b[j], acc[i][j]);
        }
    }

#pragma unroll
    for (int i = 0; i < 8; ++i) {
        const int row = row0 + 8*ty + i;
        float dnv[4];
#pragma unroll
        for (int jp = 0; jp < 4; ++jp) {
            float z0 = acc[i][2*jp]   + b11[8*tx + 2*jp];
            float z1 = acc[i][2*jp+1] + b11[8*tx + 2*jp+1];
            float jn = fmaxf(z0, 0.0f);
            float js = (z1 > 0.0f) ? z1 : 0.01f * z1;
            float delta = sqrtf(jn*jn + js*js + 1e-12f);
            float dn = 0.1f * (delta - 0.01f) / (fmaxf(delta, 1e-12f) * 0.09f);
            dnv[jp] = fminf(fmaxf(dn, 0.0f), 1.0f);
        }
        float4 dv; dv.x = dnv[0]; dv.y = dnv[1]; dv.z = dnv[2]; dv.w = dnv[3];
        *(float4*)(dnew + (size_t)row * NCOH + 4*tx) = dv;
    }
}

// ---------------------------------------------------------------------------
// K2: cummax over t; emit dmg as bf16 hi/lo into cols 128..191 of A buffers.
// ---------------------------------------------------------------------------
__global__ __launch_bounds__(64) void k2_cummax(const float* __restrict__ d)
{
    const int b = blockIdx.x;          // one batch per block
    const int c = threadIdx.x;         // 0..63
    const float* p = d + (size_t)b * NT * NCOH + c;
    unsigned short* ah = g_Ahi + (size_t)b * NT * NIN + NF + c;
    unsigned short* al = g_Alo + (size_t)b * NT * NIN + NF + c;

    float buf[8];
#pragma unroll
    for (int u = 0; u < 8; ++u) buf[u] = p[(size_t)u * NCOH];

    float m = 0.0f;
#pragma unroll 8
    for (int t = 0; t < NT - 8; ++t) {
        const int sl = t & 7;
        float v = buf[sl];
        buf[sl] = p[(size_t)(t + 8) * NCOH];
        m = fmaxf(m, v);
        unsigned short h = f2bf(m);
        ah[(size_t)t * NIN] = h;
        al[(size_t)t * NIN] = f2bf(m - bf2f(h));
    }
#pragma unroll
    for (int t = NT - 8; t < NT; ++t) {
        m = fmaxf(m, buf[t & 7]);
        unsigned short h = f2bf(m);
        ah[(size_t)t * NIN] = h;
        al[(size_t)t * NIN] = f2bf(m - bf2f(h));
    }
}

// ---------------------------------------------------------------------------
// K3: sig_tr = A @ B^T via bf16x3 MFMA (Ahi*Bhi + Ahi*Blo + Alo*Bhi = K=576).
// R6 structure (best of 3 tried: 153 vs 154 2-barrier / 190 all-register):
// triple-buffered LDS chunks, prefetch 1 ahead with global_load_lds,
// raw s_waitcnt vmcnt(4) + raw s_barrier, ONE barrier per chunk.
// R9: epilogue stores bf16 (halves sig write traffic).
// ---------------------------------------------------------------------------
__global__ __launch_bounds__(256) void k3_mfma(unsigned short* __restrict__ sig16)
{
    __shared__ unsigned short As[3][128 * 32];   // 3 x 8 KB
    __shared__ unsigned short Bs[3][128 * 32];   // 3 x 8 KB

    const int tid = threadIdx.x;
    const int lane = tid & 63, w = tid >> 6;
    const int m0 = blockIdx.y * 128;
    const int n0 = blockIdx.x * 128;          // x fastest: 3 n-tiles share A rows
    const int wm = (w >> 1) * 64, wn = (w & 1) * 64;
    const int fr = lane & 15, fq = lane >> 4;

    f32x4 acc[4][4];
#pragma unroll
    for (int mi = 0; mi < 4; ++mi)
#pragma unroll
        for (int ni = 0; ni < 4; ++ni) acc[mi][ni] = (f32x4){0.f, 0.f, 0.f, 0.f};

    // staging: 8 KB per operand chunk / 256 threads = 2 x 16 B per thread
    const int off0 = tid * 16;            // bytes in [0, 4096)
    const int off1 = tid * 16 + 4096;     // bytes in [4096, 8192)
    const int r0 = off0 >> 6, q0 = (off0 >> 4) & 3;
    const int r1 = off1 >> 6, q1 = (off1 >> 4) & 3;

    const unsigned short* Aseg[3] = {g_Ahi, g_Ahi, g_Alo};
    const unsigned short* Bseg[3] = {g_Bhi, g_Blo, g_Bhi};

    int seg_n = 0, kb_n = 0;   // of the NEXT chunk to issue

    // issue chunk 0 into buf 0
    {
        const unsigned short* Ag = Aseg[0];
        const unsigned short* Bg = Bseg[0];
        async_copy16(Ag + (size_t)(m0 + r0) * NIN + q0 * 8, (char*)As[0] + off0);
        async_copy16(Ag + (size_t)(m0 + r1) * NIN + q1 * 8, (char*)As[0] + off1);
        async_copy16(Bg + (size_t)(n0 + r0) * NIN + q0 * 8, (char*)Bs[0] + off0);
        async_copy16(Bg + (size_t)(n0 + r1) * NIN + q1 * 8, (char*)Bs[0] + off1);
        kb_n = 32;
    }

    int buf = 0;
#pragma unroll 1
    for (int c = 0; c < 17; ++c) {
        const int nbuf = (buf == 2) ? 0 : buf + 1;
        {
            const unsigned short* Ag = Aseg[seg_n];
            const unsigned short* Bg = Bseg[seg_n];
            async_copy16(Ag + (size_t)(m0 + r0) * NIN + kb_n + q0 * 8, (char*)As[nbuf] + off0);
            async_copy16(Ag + (size_t)(m0 + r1) * NIN + kb_n + q1 * 8, (char*)As[nbuf] + off1);
            async_copy16(Bg + (size_t)(n0 + r0) * NIN + kb_n + q0 * 8, (char*)Bs[nbuf] + off0);
            async_copy16(Bg + (size_t)(n0 + r1) * NIN + kb_n + q1 * 8, (char*)Bs[nbuf] + off1);
            kb_n += 32;
            if (kb_n == NIN) { kb_n = 0; ++seg_n; }
        }
        WAITCNT_VM(4);                       // own chunk-c copies landed
        __builtin_amdgcn_s_barrier();        // everyone's chunk-c landed

        bf16x8 a[4], b[4];
#pragma unroll
        for (int mi = 0; mi < 4; ++mi)
            a[mi] = *(bf16x8*)&As[buf][(wm + mi * 16 + fr) * 32 + fq * 8];
#pragma unroll
        for (int ni = 0; ni < 4; ++ni)
            b[ni] = *(bf16x8*)&Bs[buf][(wn + ni * 16 + fr) * 32 + fq * 8];
#pragma unroll
        for (int mi = 0; mi < 4; ++mi)
#pragma unroll
            for (int ni = 0; ni < 4; ++ni)
                acc[mi][ni] = __builtin_amdgcn_mfma_f32_16x16x32_bf16(
                    a[mi], b[ni], acc[mi][ni], 0, 0, 0);
        buf = nbuf;
    }

    // last chunk (c = 17), buf = 2
    WAITCNT_VM(0);
    __builtin_amdgcn_s_barrier();
    {
        bf16x8 a[4], b[4];
#pragma unroll
        for (int mi = 0; mi < 4; ++mi)
            a[mi] = *(bf16x8*)&As[buf][(wm + mi * 16 + fr) * 32 + fq * 8];
#pragma unroll
        for (int ni = 0; ni < 4; ++ni)
            b[ni] = *(bf16x8*)&Bs[buf][(wn + ni * 16 + fr) * 32 + fq * 8];
#pragma unroll
        for (int mi = 0; mi < 4; ++mi)
#pragma unroll
            for (int ni = 0; ni < 4; ++ni)
                acc[mi][ni] = __builtin_amdgcn_mfma_f32_16x16x32_bf16(
                    a[mi], b[ni], acc[mi][ni], 0, 0, 0);
    }

    // epilogue: C/D layout col=lane&15, row=(lane>>4)*4+reg; bf16 store
    const int er = fq * 4, ec = fr;
#pragma unroll
    for (int mi = 0; mi < 4; ++mi)
#pragma unroll
        for (int ni = 0; ni < 4; ++ni)
#pragma unroll
            for (int r = 0; r < 4; ++r)
                sig16[(size_t)(m0 + wm + mi * 16 + er + r) * NBS + (n0 + wn + ni * 16 + ec)]
                    = f2bf(acc[mi][ni][r]);
}

// ---------------------------------------------------------------------------
// K4: radial-return ep scan on bf16 sig_tr, scaled stress written back bf16.
// 256 blocks x 128 threads; depth-16 circular register prefetch.
// ---------------------------------------------------------------------------
__global__ __launch_bounds__(128) void k4_plast(unsigned short* __restrict__ sig16)
{
    const int b = blockIdx.x;          // one batch per block
    const int p = threadIdx.x;         // 0..127 chain
    unsigned short* s = sig16 + (size_t)b * NT * NBS + 3 * p;

    unsigned short hx[16], hy[16], hz[16];
#pragma unroll
    for (int u = 0; u < 16; ++u) {
        const unsigned short* sp = s + (size_t)u * NBS;
        hx[u] = sp[0]; hy[u] = sp[1]; hz[u] = sp[2];
    }

    float ep = 0.0f;
#pragma unroll 16
    for (int t = 0; t < NT - 16; ++t) {
        const int sl = t & 15;
        float sxx = bf2f(hx[sl]), syy = bf2f(hy[sl]), txy = bf2f(hz[sl]);
        {
            const unsigned short* sp = s + (size_t)(t + 16) * NBS;
            hx[sl] = sp[0]; hy[sl] = sp[1]; hz[sl] = sp[2];
        }
        float seq = sqrtf(sxx*sxx - sxx*syy + syy*syy + 3.0f*txy*txy + 1e-12f);
        float fy = seq - (10.0f + 100.0f * ep);
        float dep = (fy > 0.0f) ? (fy / H3G) : 0.0f;
        ep += dep;
        float scale = (fy > 0.0f) ? ((10.0f + 100.0f * ep) / seq) : 1.0f;
        unsigned short* op = s + (size_t)t * NBS;
        op[0] = f2bf(sxx * scale); op[1] = f2bf(syy * scale); op[2] = f2bf(txy * scale);
    }
#pragma unroll
    for (int t = NT - 16; t < NT; ++t) {
        const int sl = t & 15;
        float sxx = bf2f(hx[sl]), syy = bf2f(hy[sl]), txy = bf2f(hz[sl]);
        float seq = sqrtf(sxx*sxx - sxx*syy + syy*syy + 3.0f*txy*txy + 1e-12f);
        float fy = seq - (10.0f + 100.0f * ep);
        float dep = (fy > 0.0f) ? (fy / H3G) : 0.0f;
        ep += dep;
        float scale = (fy > 0.0f) ? ((10.0f + 100.0f * ep) / seq) : 1.0f;
        unsigned short* op = s + (size_t)t * NBS;
        op[0] = f2bf(sxx * scale); op[1] = f2bf(syy * scale); op[2] = f2bf(txy * scale);
    }
}

// ---------------------------------------------------------------------------
// K5: out = softplus(sig @ W2^T). Row-per-thread, zero cross-lane ops.
// bf16 rows: 48 x ushort8 loads, W2 broadcast from LDS.
// ---------------------------------------------------------------------------
__global__ __launch_bounds__(256) void k5_out(
    const unsigned short* __restrict__ sig16, const float* __restrict__ W2,
    float* __restrict__ out)
{
    __shared__ float W2s[6][NBS];
    const int tid = threadIdx.x;
    for (int i = tid; i < 6 * NBS; i += 256) W2s[i / NBS][i % NBS] = W2[i];
    __syncthreads();

    const int row = blockIdx.x * 256 + tid;     // 512 blocks x 256 = NROWS
    const ushort8v* sv = (const ushort8v*)(sig16 + (size_t)row * NBS);

    float acc[6] = {0, 0, 0, 0, 0, 0};
#pragma unroll 4
    for (int q = 0; q < NBS / 8; ++q) {
        ushort8v u = sv[q];
        float v[8];
#pragma unroll
        for (int i = 0; i < 8; ++i) v[i] = bf2f(u[i]);
#pragma unroll
        for (int o = 0; o < 6; ++o) {
            float4 w0 = *(const float4*)&W2s[o][8 * q];
            float4 w1 = *(const float4*)&W2s[o][8 * q + 4];
            acc[o] = fmaf(v[0], w0.x, acc[o]); acc[o] = fmaf(v[1], w0.y, acc[o]);
            acc[o] = fmaf(v[2], w0.z, acc[o]); acc[o] = fmaf(v[3], w0.w, acc[o]);
            acc[o] = fmaf(v[4], w1.x, acc[o]); acc[o] = fmaf(v[5], w1.y, acc[o]);
            acc[o] = fmaf(v[6], w1.z, acc[o]); acc[o] = fmaf(v[7], w1.w, acc[o]);
        }
    }

    float res[6];
#pragma unroll
    for (int o = 0; o < 6; ++o) {
        float z = acc[o];
        res[o] = fmaxf(z, 0.0f) + log1pf(expf(-fabsf(z)));
    }
    float* op = out + (size_t)row * 6;
#pragma unroll
    for (int o = 0; o < 6; ++o) op[o] = res[o];
}

// ---------------------------------------------------------------------------
extern "C" void kernel_launch(void* const* d_in, const int* in_sizes, int n_in,
                              void* d_out, int out_size, void* d_ws, size_t ws_size,
                              hipStream_t stream)
{
    const float* x   = (const float*)d_in[0];
    const float* W11 = (const float*)d_in[1];
    const float* b11 = (const float*)d_in[2];
    const float* W12 = (const float*)d_in[3];
    const float* W2  = (const float*)d_in[4];
    float* out = (float*)d_out;

    // ws layout: dnew [NROWS*64] fp32 (32MB) | sig16 [NROWS*384] bf16 (96MB)
    float* dnew = (float*)d_ws;
    unsigned short* sig16 = (unsigned short*)((char*)d_ws + (size_t)NROWS * NCOH * sizeof(float));

    k0_w12<<<(NBS * NIN) / 256, 256, 0, stream>>>(W12);
    k1_fc11<<<NROWS / 128, 256, 0, stream>>>(x, W11, b11, dnew);
    k2_cummax<<<NB, 64, 0, stream>>>(dnew);
    k3_mfma<<<dim3(3, NROWS / 128), 256, 0, stream>>>(sig16);
    k4_plast<<<NB, 128, 0, stream>>>(sig16);
    k5_out<<<NROWS / 256, 256, 0, stream>>>(sig16, W2, out);
}

// Round 10
// 382.683 us; speedup vs baseline: 1.9014x; 1.2674x over previous
//
#include <hip/hip_runtime.h>
#include <hip/hip_bf16.h>
#include <math.h>

// Problem dims
#define NB 256
#define NT 512
#define NF 128
#define NCOH 64         // coh_pts
#define NIN 192         // F + coh_pts
#define NBS 384         // 3*bulk_pts
#define NROWS (NB*NT)   // 131072

// Material constants (match fp64->fp32 of reference)
#define C11 1098.9010989010989f
#define C12 329.67032967032966f
#define C33 384.61538461538464f
#define H3G 1253.8461538461538f   // 3*G + HARD

typedef __attribute__((ext_vector_type(8))) short bf16x8;   // 8 bf16 = 4 VGPR
typedef __attribute__((ext_vector_type(4))) float f32x4;    // MFMA acc
typedef __attribute__((ext_vector_type(8))) unsigned short ushort8v;

// s_waitcnt with only vmcnt constrained (expcnt=7, lgkmcnt=15 = no-wait)
#define WAITCNT_VM(N) __builtin_amdgcn_s_waitcnt(0x0F70 | ((N) & 15) | (((N) >> 4) << 14))

// A operand, single bf16 (R10: Alo dropped — error ~2^-9*|sig|, same scale as
// validated bf16-sig storage). TILED layout: [kchunk 0..5][row 0..NROWS)[32]
// so one (m-tile, kchunk) stage = 8 KB contiguous.
#define PS ((size_t)NROWS * 32)     // plane stride in ushorts
__device__ unsigned short g_Ahi[6 * PS];
__device__ unsigned short g_Bhi[NBS * NIN];             // D-folded W12 hi
__device__ unsigned short g_Blo[NBS * NIN];             // D-folded W12 lo

static __device__ __forceinline__ unsigned short f2bf(float v) {
    __hip_bfloat16 h = __float2bfloat16(v);
    return *reinterpret_cast<unsigned short*>(&h);
}
static __device__ __forceinline__ float bf2f(unsigned short u) {
    unsigned int x = ((unsigned int)u) << 16;
    return *reinterpret_cast<float*>(&x);
}
static __device__ __forceinline__ void async_copy16(const void* g, void* l) {
    __builtin_amdgcn_global_load_lds(
        (const __attribute__((address_space(1))) unsigned int*)g,
        (__attribute__((address_space(3))) unsigned int*)l, 16, 0, 0);
}

// ---------------------------------------------------------------------------
// K0: fold plane-stress D into W12 and split to bf16 hi/lo (B stays exact-ish).
// ---------------------------------------------------------------------------
__global__ __launch_bounds__(256) void k0_w12(const float* __restrict__ W12)
{
    const int idx = blockIdx.x * 256 + threadIdx.x;   // < 384*192 = 73728
    const int r = idx / NIN, i = idx - r * NIN;
    const int p = r / 3, j = r - 3 * p;
    const float* w = W12 + (size_t)(3 * p) * NIN;
    float v;
    if (j == 0)      v = C11 * w[i]           + C12 * w[NIN + i];
    else if (j == 1) v = C12 * w[i]           + C11 * w[NIN + i];
    else             v = C33 * w[2 * NIN + i];
    unsigned short h = f2bf(v);
    g_Bhi[idx] = h;
    g_Blo[idx] = f2bf(v - bf2f(h));
}

// ---------------------------------------------------------------------------
// KX: x (fp32) -> bf16 into tiled A planes 0..3 (cols 0..127). Coalesced:
// thread = (row, 8-element group); one ushort8 (16B) store.
// ---------------------------------------------------------------------------
__global__ __launch_bounds__(256) void kx_split(const float* __restrict__ x)
{
    const int idx = blockIdx.x * 256 + threadIdx.x;   // NROWS*16
    const int row = idx >> 4, g = idx & 15;
    const float* src = x + (size_t)row * NF + g * 8;
    float4 v0 = ((const float4*)src)[0];
    float4 v1 = ((const float4*)src)[1];
    ushort8v h;
    h[0] = f2bf(v0.x); h[1] = f2bf(v0.y); h[2] = f2bf(v0.z); h[3] = f2bf(v0.w);
    h[4] = f2bf(v1.x); h[5] = f2bf(v1.y); h[6] = f2bf(v1.z); h[7] = f2bf(v1.w);
    *(ushort8v*)(g_Ahi + (size_t)(g >> 2) * PS + (size_t)row * 32 + (g & 3) * 8) = h;
}

// ---------------------------------------------------------------------------
// K1: jumps = leaky_relu(x @ W11^T + b11); d_new. fp32 GEMM (R5 form —
// in-loop split emission removed; it cost ~+40 us of scattered stores).
// ---------------------------------------------------------------------------
__global__ __launch_bounds__(256, 2) void k1_fc11(
    const float* __restrict__ x, const float* __restrict__ W11,
    const float* __restrict__ b11, float* __restrict__ dnew)
{
    __shared__ float As[16][132];
    __shared__ float Bs[16][128];
    const int tid = threadIdx.x;
    const int row0 = blockIdx.x * 128;
    const int tx = tid & 15, ty = tid >> 4;

    float acc[8][8];
#pragma unroll
    for (int i = 0; i < 8; ++i)
#pragma unroll
        for (int j = 0; j < 8; ++j) acc[i][j] = 0.0f;

    const int lr = tid >> 2;
    const int lk = (tid & 3) * 4;
    const int bn = tid >> 1;
    const int bk = (tid & 1) * 8;

    for (int kc = 0; kc < 8; ++kc) {
        const int k0 = kc * 16;
        float4 a0 = *(const float4*)(x + (size_t)(row0 + lr) * NF + k0 + lk);
        float4 a1 = *(const float4*)(x + (size_t)(row0 + lr + 64) * NF + k0 + lk);
        float4 w0 = *(const float4*)(W11 + (size_t)bn * NF + k0 + bk);
        float4 w1 = *(const float4*)(W11 + (size_t)bn * NF + k0 + bk + 4);
        __syncthreads();
        As[lk+0][lr] = a0.x; As[lk+1][lr] = a0.y; As[lk+2][lr] = a0.z; As[lk+3][lr] = a0.w;
        As[lk+0][lr+64] = a1.x; As[lk+1][lr+64] = a1.y; As[lk+2][lr+64] = a1.z; As[lk+3][lr+64] = a1.w;
        Bs[bk+0][bn] = w0.x; Bs[bk+1][bn] = w0.y; Bs[bk+2][bn] = w0.z; Bs[bk+3][bn] = w0.w;
        Bs[bk+4][bn] = w1.x; Bs[bk+5][bn] = w1.y; Bs[bk+6][bn] = w1.z; Bs[bk+7][bn] = w1.w;
        __syncthreads();
#pragma unroll
        for (int k = 0; k < 16; ++k) {
            float4 av0 = *(const float4*)&As[k][8*ty];
            float4 av1 = *(const float4*)&As[k][8*ty+4];
            float4 bv0 = *(const float4*)&Bs[k][8*tx];
            float4 bv1 = *(const float4*)&Bs[k][8*tx+4];
            float a[8] = {av0.x,av0.y,av0.z,av0.w,av1.x,av1.y,av1.z,av1.w};
            float b[8] = {bv0.x,bv0.y,bv0.z,bv0.w,bv1.x,bv1.y,bv1.z,bv1.w};
#pragma unroll
            for (int i = 0; i < 8; ++i)
#pragma unroll
                for (int j = 0; j < 8; ++j)
                    acc[i][j] = fmaf(a[i], b[j], acc[i][j]);
        }
    }

#pragma unroll
    for (int i = 0; i < 8; ++i) {
        const int row = row0 + 8*ty + i;
        float dnv[4];
#pragma unroll
        for (int jp = 0; jp < 4; ++jp) {
            float z0 = acc[i][2*jp]   + b11[8*tx + 2*jp];
            float z1 = acc[i][2*jp+1] + b11[8*tx + 2*jp+1];
            float jn = fmaxf(z0, 0.0f);
            float js = (z1 > 0.0f) ? z1 : 0.01f * z1;
            float delta = sqrtf(jn*jn + js*js + 1e-12f);
            float dn = 0.1f * (delta - 0.01f) / (fmaxf(delta, 1e-12f) * 0.09f);
            dnv[jp] = fminf(fmaxf(dn, 0.0f), 1.0f);
        }
        float4 dv; dv.x = dnv[0]; dv.y = dnv[1]; dv.z = dnv[2]; dv.w = dnv[3];
        *(float4*)(dnew + (size_t)row * NCOH + 4*tx) = dv;
    }
}

// ---------------------------------------------------------------------------
// K2 (two-phase parallel cummax, 8 segments of 64 t -> 2048 waves not 256):
// k2a: per-(b,seg,c) segment max. k2b: prefix-carry + rewalk, emit bf16 into
// tiled A planes 4..5 (cols 128..191).
// ---------------------------------------------------------------------------
__global__ __launch_bounds__(64) void k2a(const float* __restrict__ d,
                                          float* __restrict__ totals)
{
    const int b = blockIdx.x >> 3, seg = blockIdx.x & 7;
    const int c = threadIdx.x;
    const float* p = d + (size_t)b * NT * NCOH + (size_t)seg * 64 * NCOH + c;
    float m = 0.0f;
#pragma unroll 8
    for (int i = 0; i < 64; ++i) m = fmaxf(m, p[(size_t)i * NCOH]);
    totals[(size_t)(b * 8 + seg) * 64 + c] = m;
}

__global__ __launch_bounds__(64) void k2b(const float* __restrict__ d,
                                          const float* __restrict__ totals)
{
    const int b = blockIdx.x >> 3, seg = blockIdx.x & 7;
    const int c = threadIdx.x;
    float carry = 0.0f;
    for (int s = 0; s < seg; ++s)
        carry = fmaxf(carry, totals[(size_t)(b * 8 + s) * 64 + c]);
    const float* p = d + (size_t)b * NT * NCOH + (size_t)seg * 64 * NCOH + c;
    unsigned short* ah = g_Ahi + (size_t)(4 + (c >> 5)) * PS
                       + (size_t)(b * NT + seg * 64) * 32 + (c & 31);
    float m = carry;
#pragma unroll 8
    for (int i = 0; i < 64; ++i) {
        m = fmaxf(m, p[(size_t)i * NCOH]);
        ah[(size_t)i * 32] = f2bf(m);
    }
}

// ---------------------------------------------------------------------------
// K3: sig_tr = A @ B^T via MFMA, A single bf16, B hi+lo:
// C = Ahi*(Bhi + Blo). A-stationary: 6 chunks, per chunk stage {Ahi,Bhi,Blo}
// (3 x 8 KB contiguous tiles, 6 async copies/thread-pair) then 32 MFMA.
// Triple-buffered, vmcnt(6) + raw barrier, ONE barrier per chunk (6 total
// vs 18 in R9 — 2.67x more MFMA per staging phase, LDS traffic halved).
// ---------------------------------------------------------------------------
__global__ __launch_bounds__(256) void k3_mfma(unsigned short* __restrict__ sig16)
{
    __shared__ unsigned short Ah[3][4096];   // 3 x 8 KB
    __shared__ unsigned short Bh[3][4096];
    __shared__ unsigned short Bl[3][4096];

    const int tid = threadIdx.x;
    const int lane = tid & 63, w = tid >> 6;
    const int m0 = blockIdx.y * 128;
    const int n0 = blockIdx.x * 128;
    const int wm = (w >> 1) * 64, wn = (w & 1) * 64;
    const int fr = lane & 15, fq = lane >> 4;

    f32x4 acc[4][4];
#pragma unroll
    for (int mi = 0; mi < 4; ++mi)
#pragma unroll
        for (int ni = 0; ni < 4; ++ni) acc[mi][ni] = (f32x4){0.f, 0.f, 0.f, 0.f};

    // per-thread staging: 2 x 16 B per 8 KB tile
    const int off0 = tid * 16;            // bytes [0, 4096)
    const int off1 = tid * 16 + 4096;     // bytes [4096, 8192)
    const int r0 = off0 >> 6, q0 = (off0 >> 4) & 3;   // B addressing
    const int r1 = off1 >> 6, q1 = (off1 >> 4) & 3;

    // A tiled source: plane kc, contiguous 8 KB at m0*32
    const char* Abase = (const char*)(g_Ahi + (size_t)m0 * 32);
    const size_t Aplane = PS * 2;         // bytes per plane

#define ISSUE_CHUNK(kc, buf_)                                                   \
    {                                                                           \
        const char* As_ = Abase + (size_t)(kc) * Aplane;                        \
        async_copy16(As_ + off0, (char*)Ah[buf_] + off0);                       \
        async_copy16(As_ + off1, (char*)Ah[buf_] + off1);                       \
        async_copy16(g_Bhi + (size_t)(n0 + r0) * NIN + (kc) * 32 + q0 * 8,      \
                     (char*)Bh[buf_] + off0);                                   \
        async_copy16(g_Bhi + (size_t)(n0 + r1) * NIN + (kc) * 32 + q1 * 8,      \
                     (char*)Bh[buf_] + off1);                                   \
        async_copy16(g_Blo + (size_t)(n0 + r0) * NIN + (kc) * 32 + q0 * 8,      \
                     (char*)Bl[buf_] + off0);                                   \
        async_copy16(g_Blo + (size_t)(n0 + r1) * NIN + (kc) * 32 + q1 * 8,      \
                     (char*)Bl[buf_] + off1);                                   \
    }

    ISSUE_CHUNK(0, 0);

    int buf = 0;
#pragma unroll 1
    for (int c = 0; c < 5; ++c) {
        const int nbuf = (buf == 2) ? 0 : buf + 1;
        ISSUE_CHUNK(c + 1, nbuf);
        WAITCNT_VM(6);                       // own chunk-c copies landed
        __builtin_amdgcn_s_barrier();        // everyone's chunk-c landed

        bf16x8 a[4], bh[4], bl[4];
#pragma unroll
        for (int mi = 0; mi < 4; ++mi)
            a[mi] = *(bf16x8*)&Ah[buf][(wm + mi * 16 + fr) * 32 + fq * 8];
#pragma unroll
        for (int ni = 0; ni < 4; ++ni) {
            bh[ni] = *(bf16x8*)&Bh[buf][(wn + ni * 16 + fr) * 32 + fq * 8];
            bl[ni] = *(bf16x8*)&Bl[buf][(wn + ni * 16 + fr) * 32 + fq * 8];
        }
#pragma unroll
        for (int mi = 0; mi < 4; ++mi)
#pragma unroll
            for (int ni = 0; ni < 4; ++ni) {
                acc[mi][ni] = __builtin_amdgcn_mfma_f32_16x16x32_bf16(
                    a[mi], bh[ni], acc[mi][ni], 0, 0, 0);
                acc[mi][ni] = __builtin_amdgcn_mfma_f32_16x16x32_bf16(
                    a[mi], bl[ni], acc[mi][ni], 0, 0, 0);
            }
        buf = nbuf;
    }

    // last chunk (c = 5), buf = 5%3 = 2
    WAITCNT_VM(0);
    __builtin_amdgcn_s_barrier();
    {
        bf16x8 a[4], bh[4], bl[4];
#pragma unroll
        for (int mi = 0; mi < 4; ++mi)
            a[mi] = *(bf16x8*)&Ah[buf][(wm + mi * 16 + fr) * 32 + fq * 8];
#pragma unroll
        for (int ni = 0; ni < 4; ++ni) {
            bh[ni] = *(bf16x8*)&Bh[buf][(wn + ni * 16 + fr) * 32 + fq * 8];
            bl[ni] = *(bf16x8*)&Bl[buf][(wn + ni * 16 + fr) * 32 + fq * 8];
        }
#pragma unroll
        for (int mi = 0; mi < 4; ++mi)
#pragma unroll
            for (int ni = 0; ni < 4; ++ni) {
                acc[mi][ni] = __builtin_amdgcn_mfma_f32_16x16x32_bf16(
                    a[mi], bh[ni], acc[mi][ni], 0, 0, 0);
                acc[mi][ni] = __builtin_amdgcn_mfma_f32_16x16x32_bf16(
                    a[mi], bl[ni], acc[mi][ni], 0, 0, 0);
            }
    }
#undef ISSUE_CHUNK

    // epilogue: C/D layout col=lane&15, row=(lane>>4)*4+reg; bf16 store
    const int er = fq * 4, ec = fr;
#pragma unroll
    for (int mi = 0; mi < 4; ++mi)
#pragma unroll
        for (int ni = 0; ni < 4; ++ni)
#pragma unroll
            for (int r = 0; r < 4; ++r)
                sig16[(size_t)(m0 + wm + mi * 16 + er + r) * NBS + (n0 + wn + ni * 16 + ec)]
                    = f2bf(acc[mi][ni][r]);
}

// ---------------------------------------------------------------------------
// K4: radial-return ep scan on bf16 sig_tr, scaled stress written back bf16.
// 256 blocks x 128 threads; depth-16 circular register prefetch.
// ---------------------------------------------------------------------------
__global__ __launch_bounds__(128) void k4_plast(unsigned short* __restrict__ sig16)
{
    const int b = blockIdx.x;
    const int p = threadIdx.x;
    unsigned short* s = sig16 + (size_t)b * NT * NBS + 3 * p;

    unsigned short hx[16], hy[16], hz[16];
#pragma unroll
    for (int u = 0; u < 16; ++u) {
        const unsigned short* sp = s + (size_t)u * NBS;
        hx[u] = sp[0]; hy[u] = sp[1]; hz[u] = sp[2];
    }

    float ep = 0.0f;
#pragma unroll 16
    for (int t = 0; t < NT - 16; ++t) {
        const int sl = t & 15;
        float sxx = bf2f(hx[sl]), syy = bf2f(hy[sl]), txy = bf2f(hz[sl]);
        {
            const unsigned short* sp = s + (size_t)(t + 16) * NBS;
            hx[sl] = sp[0]; hy[sl] = sp[1]; hz[sl] = sp[2];
        }
        float seq = sqrtf(sxx*sxx - sxx*syy + syy*syy + 3.0f*txy*txy + 1e-12f);
        float fy = seq - (10.0f + 100.0f * ep);
        float dep = (fy > 0.0f) ? (fy / H3G) : 0.0f;
        ep += dep;
        float scale = (fy > 0.0f) ? ((10.0f + 100.0f * ep) / seq) : 1.0f;
        unsigned short* op = s + (size_t)t * NBS;
        op[0] = f2bf(sxx * scale); op[1] = f2bf(syy * scale); op[2] = f2bf(txy * scale);
    }
#pragma unroll
    for (int t = NT - 16; t < NT; ++t) {
        const int sl = t & 15;
        float sxx = bf2f(hx[sl]), syy = bf2f(hy[sl]), txy = bf2f(hz[sl]);
        float seq = sqrtf(sxx*sxx - sxx*syy + syy*syy + 3.0f*txy*txy + 1e-12f);
        float fy = seq - (10.0f + 100.0f * ep);
        float dep = (fy > 0.0f) ? (fy / H3G) : 0.0f;
        ep += dep;
        float scale = (fy > 0.0f) ? ((10.0f + 100.0f * ep) / seq) : 1.0f;
        unsigned short* op = s + (size_t)t * NBS;
        op[0] = f2bf(sxx * scale); op[1] = f2bf(syy * scale); op[2] = f2bf(txy * scale);
    }
}

// ---------------------------------------------------------------------------
// K5: out = softplus(sig @ W2^T). Row-per-thread, zero cross-lane ops.
// ---------------------------------------------------------------------------
__global__ __launch_bounds__(256) void k5_out(
    const unsigned short* __restrict__ sig16, const float* __restrict__ W2,
    float* __restrict__ out)
{
    __shared__ float W2s[6][NBS];
    const int tid = threadIdx.x;
    for (int i = tid; i < 6 * NBS; i += 256) W2s[i / NBS][i % NBS] = W2[i];
    __syncthreads();

    const int row = blockIdx.x * 256 + tid;
    const ushort8v* sv = (const ushort8v*)(sig16 + (size_t)row * NBS);

    float acc[6] = {0, 0, 0, 0, 0, 0};
#pragma unroll 4
    for (int q = 0; q < NBS / 8; ++q) {
        ushort8v u = sv[q];
        float v[8];
#pragma unroll
        for (int i = 0; i < 8; ++i) v[i] = bf2f(u[i]);
#pragma unroll
        for (int o = 0; o < 6; ++o) {
            float4 w0 = *(const float4*)&W2s[o][8 * q];
            float4 w1 = *(const float4*)&W2s[o][8 * q + 4];
            acc[o] = fmaf(v[0], w0.x, acc[o]); acc[o] = fmaf(v[1], w0.y, acc[o]);
            acc[o] = fmaf(v[2], w0.z, acc[o]); acc[o] = fmaf(v[3], w0.w, acc[o]);
            acc[o] = fmaf(v[4], w1.x, acc[o]); acc[o] = fmaf(v[5], w1.y, acc[o]);
            acc[o] = fmaf(v[6], w1.z, acc[o]); acc[o] = fmaf(v[7], w1.w, acc[o]);
        }
    }

    float res[6];
#pragma unroll
    for (int o = 0; o < 6; ++o) {
        float z = acc[o];
        res[o] = fmaxf(z, 0.0f) + log1pf(expf(-fabsf(z)));
    }
    float* op = out + (size_t)row * 6;
#pragma unroll
    for (int o = 0; o < 6; ++o) op[o] = res[o];
}

// ---------------------------------------------------------------------------
extern "C" void kernel_launch(void* const* d_in, const int* in_sizes, int n_in,
                              void* d_out, int out_size, void* d_ws, size_t ws_size,
                              hipStream_t stream)
{
    const float* x   = (const float*)d_in[0];
    const float* W11 = (const float*)d_in[1];
    const float* b11 = (const float*)d_in[2];
    const float* W12 = (const float*)d_in[3];
    const float* W2  = (const float*)d_in[4];
    float* out = (float*)d_out;

    // ws: dnew 32MB @0 | sig16 96MB @32MB | totals 512KB @128MB
    float* dnew = (float*)d_ws;
    unsigned short* sig16 = (unsigned short*)((char*)d_ws + (size_t)NROWS * NCOH * sizeof(float));
    float* totals = (float*)((char*)d_ws + (size_t)128 * 1024 * 1024);

    k0_w12<<<(NBS * NIN) / 256, 256, 0, stream>>>(W12);
    kx_split<<<(NROWS * 16) / 256, 256, 0, stream>>>(x);
    k1_fc11<<<NROWS / 128, 256, 0, stream>>>(x, W11, b11, dnew);
    k2a<<<NB * 8, 64, 0, stream>>>(dnew, totals);
    k2b<<<NB * 8, 64, 0, stream>>>(dnew, totals);
    k3_mfma<<<dim3(3, NROWS / 128), 256, 0, stream>>>(sig16);
    k4_plast<<<NB, 128, 0, stream>>>(sig16);
    k5_out<<<NROWS / 256, 256, 0, stream>>>(sig16, W2, out);
}